// Round 19
// baseline (48.846 us; speedup 1.0000x reference)
//
#include <hip/hip_runtime.h>
#include <hip/hip_bf16.h>

#define BB 4
#define SS 2048
#define DD 16
#define KK 204      // max(1, int(2048*0.1))

typedef __attribute__((ext_vector_type(8))) short short8;
typedef __attribute__((ext_vector_type(4))) float f32x4;

__device__ inline short f2bf(float x) {
  __hip_bfloat16 b = __float2bfloat16(x);
  return *reinterpret_cast<short*>(&b);
}

// ---- SINGLE dispatch (256 blocks x 1024 thr; 2 m-tiles/block, 1 block/CU) ----
// 1024-thr blocks fix 16 waves co-resident (4/SIMD) -> VGPR budget 512/thr,
// NO occupancy cliff / spill heuristic (the R14/R17 failure mode was the
// 512-thr compiler 128-VGPR cap). Per block: in-block scores for the 2 rows
// each thread's keys need (redundant across blocks, deterministic, L2-resident
// re-reads) + ONE radix select (R11-proven 1024-thr form) + ONE gather + ONE
// kvb serving TWO m-tiles' j-loops (waves 0-7 tile0, 8-15 tile1).
// key = monotone(score)<<11 | (2047-i); unique keys -> "key >= K*" == jax
// top_k set; 4 passes x 11 bits. hist aliases first 8KB of s_kvb; red
// (16x512) aliases s_kvb in the epilogue.
// MFMA frags (16x16x32 bf16): A lane l: [m=l&15][k=8*(l>>4)+i];
// B lane l: [k=8*(l>>4)+i][n=l&15]; D lane l reg r: [m=4*(l>>4)+r][n=l&15].
__global__ void __launch_bounds__(1024) mega_kernel(
    const float* __restrict__ full, const float* __restrict__ sw1,
    const float* __restrict__ sb1, const float* __restrict__ sw2,
    const float* __restrict__ sb2, const float* __restrict__ mw1,
    const float* __restrict__ mb1, const float* __restrict__ mw2,
    const float* __restrict__ mb2, const float* __restrict__ mw3,
    const float* __restrict__ mb3, float* __restrict__ out) {
  int bs_base = blockIdx.x * 32;     // 2 m-tiles of 16 rows
  int b = bs_base >> 11;             // 64 blocks per batch
  int t = threadIdx.x;
  int w = t >> 6;                    // 0..15
  int l = t & 63;
  int mt = w >> 3;                   // m-tile 0/1
  int wl = w & 7;                    // wave within tile
  int ml = l & 15;
  int g = l >> 4;

  __shared__ float s_kvb[KK * 64];   // 52224 B; aliased: hist / red
  __shared__ float qs[32 * 64];      // 8 KB (both tiles)
  __shared__ float xs[32 * 16];      // 2 KB
  __shared__ float s_xsel[KK * DD];  // 12.75 KB
  __shared__ float swT[32][16];      // 2 KB [n][k]
  __shared__ float sb1s[32], sw2s[32];
  __shared__ int s_idx[KK];
  __shared__ int wtot[16];
  __shared__ unsigned long long s_pfx;
  __shared__ int s_r;
  int* hist = (int*)s_kvb;                    // first 2048 ints
  float (*red)[512] = (float(*)[512])s_kvb;   // epilogue alias (16x512)

  // stage score weights + raw rows
  if (t < 512) { int n = t & 31, k = t >> 5; swT[n][k] = sw1[k * 32 + n]; }
  if (t < 32) { sb1s[t] = sb1[t]; sw2s[t] = sw2[t]; }
  if (t < 512) xs[t] = full[bs_base * DD + t];
  if (t == 0) { s_pfx = 0ull; s_r = KK; }
  __syncthreads();  // swT/sb1s/sw2s/xs visible

  // ---- qpart for both tiles (published by first radix barrier) ----
  {
    int r = t >> 5, n = t & 31;
    float q0 = 0.f, q1 = 0.f;
#pragma unroll
    for (int k = 0; k < 16; k++) {
      float xv = xs[r * 16 + k];
      q0 += xv * mw1[k * 64 + n];        // w_q = mw1[:16]
      q1 += xv * mw1[k * 64 + n + 32];
    }
    qs[r * 64 + n] = q0;
    qs[r * 64 + n + 32] = q1;
  }

  // ---- in-block scores for rows t, t+1024 -> keys (R15-proven FMA order) ----
  float sb2v = sb2[0];
  unsigned long long key[2];
#pragma unroll
  for (int e = 0; e < 2; e++) {
    int i = t + e * 1024;
    const float* xp = full + (b * SS + i) * DD;
    f32x4 x0 = *(const f32x4*)(xp);
    f32x4 x1 = *(const f32x4*)(xp + 4);
    f32x4 x2 = *(const f32x4*)(xp + 8);
    f32x4 x3 = *(const f32x4*)(xp + 12);
    float sc = sb2v;
#pragma unroll
    for (int n = 0; n < 32; n++) {
      const f32x4* wp = (const f32x4*)&swT[n][0];
      f32x4 w0 = wp[0], w1 = wp[1], w2 = wp[2], w3 = wp[3];
      float a = sb1s[n];
#pragma unroll
      for (int k = 0; k < 4; k++) a += x0[k] * w0[k];
#pragma unroll
      for (int k = 0; k < 4; k++) a += x1[k] * w1[k];
#pragma unroll
      for (int k = 0; k < 4; k++) a += x2[k] * w2[k];
#pragma unroll
      for (int k = 0; k < 4; k++) a += x3[k] * w3[k];
      sc += fmaxf(a, 0.f) * sw2s[n];
    }
    unsigned u = __float_as_uint(sc);
    u = (u & 0x80000000u) ? ~u : (u | 0x80000000u);  // order-preserving asc
    key[e] = ((unsigned long long)u << 11) | (unsigned)(SS - 1 - i);
  }

  // ---- radix select (R11/R18-proven 1024-thread form) ----
  for (int pass = 0; pass < 4; pass++) {
    int s = 33 - pass * 11;
    hist[t] = 0;
    hist[t + 1024] = 0;
    __syncthreads();                    // hist zeroed; s_pfx/s_r/qs visible
    unsigned long long pfx = s_pfx;
    int r = s_r;
#pragma unroll
    for (int e = 0; e < 2; e++)
      if ((key[e] >> (s + 11)) == pfx)
        atomicAdd(&hist[(int)((key[e] >> s) & 0x7FF)], 1);
    __syncthreads();
    // thread owns bins 2t, 2t+1
    int loc0 = hist[2 * t], loc1 = hist[2 * t + 1];
    int ls0 = loc0 + loc1, ls1 = loc1;  // suffix sums within the pair
    int tot = ls0;
    int incl = tot;  // wave inclusive suffix-scan (lanes >= l)
#pragma unroll
    for (int off = 1; off < 64; off <<= 1) {
      int o = __shfl_down(incl, off);
      incl += (l + off < 64) ? o : 0;
    }
    if (l == 0) wtot[w] = incl;
    __syncthreads();
    int waveoff = 0;
    for (int ww = w + 1; ww < 16; ww++) waveoff += wtot[ww];
    int excl = waveoff + (incl - tot);  // sum over threads > t
    int sufs0 = ls0 + excl, sufs1 = ls1 + excl;
    if (sufs0 >= r && sufs1 < r) {      // bin 2t is the boundary
      s_pfx = (pfx << 11) | (unsigned)(2 * t);
      s_r = r - sufs1;
    }
    if (sufs1 >= r && excl < r) {       // bin 2t+1 is the boundary
      s_pfx = (pfx << 11) | (unsigned)(2 * t + 1);
      s_r = r - excl;
    }
    __syncthreads();
  }

  unsigned long long kstar = s_pfx;
  // deterministic compaction ordered by (t, e)
  bool sel0 = (key[0] >= kstar), sel1 = (key[1] >= kstar);
  int c = (sel0 ? 1 : 0) + (sel1 ? 1 : 0);
  int p = c;  // wave inclusive prefix (lanes <= l)
#pragma unroll
  for (int off = 1; off < 64; off <<= 1) {
    int o = __shfl_up(p, off);
    p += (l >= off) ? o : 0;
  }
  if (l == 63) wtot[w] = p;
  __syncthreads();
  int base = 0;
  for (int ww = 0; ww < w; ww++) base += wtot[ww];
  int pos = base + p - c;
  if (sel0) s_idx[pos++] = t;
  if (sel1) s_idx[pos] = t + 1024;
  __syncthreads();  // s_idx ready

  // ---- vectorized gather of selected rows (f32x4; 4 lanes per 64B row) ----
  {
    f32x4* dst = (f32x4*)s_xsel;
    for (int i = t; i < KK * 4; i += 1024) {
      int j = i >> 2, qu = i & 3;
      dst[i] = ((const f32x4*)(full + (b * SS + s_idx[j]) * DD))[qu];
    }
  }
  float wreg[16];
#pragma unroll
  for (int k = 0; k < 16; k++)
    wreg[k] = mw1[(16 + k) * 64 + l] + mw1[(32 + k) * 64 + l];
  float biasv = mb1[l];
  __syncthreads();  // s_xsel ready; hist region free

  // ---- kvb into LDS (wave w: j = w, w+16, ...; same inner FMA order) ----
  for (int j = w; j < KK; j += 16) {
    const f32x4* xr = (const f32x4*)(s_xsel + j * DD);
    f32x4 x0 = xr[0], x1 = xr[1], x2 = xr[2], x3 = xr[3];
    float a = biasv;
#pragma unroll
    for (int k = 0; k < 4; k++) a += x0[k] * wreg[k];
#pragma unroll
    for (int k = 0; k < 4; k++) a += x1[k] * wreg[4 + k];
#pragma unroll
    for (int k = 0; k < 4; k++) a += x2[k] * wreg[8 + k];
#pragma unroll
    for (int k = 0; k < 4; k++) a += x3[k] * wreg[12 + k];
    s_kvb[j * 64 + l] = a;
  }

  short8 bfrag[2][2];  // [ntile][khalf]
#pragma unroll
  for (int nt = 0; nt < 2; nt++)
#pragma unroll
    for (int kh = 0; kh < 2; kh++)
#pragma unroll
      for (int i = 0; i < 8; i++) {
        int k = kh * 32 + 8 * g + i;
        bfrag[nt][kh][i] = f2bf(mw2[k * 32 + nt * 16 + ml]);
      }
  f32x4 biasfrag[2];
#pragma unroll
  for (int nt = 0; nt < 2; nt++) {
    float bv = mb2[nt * 16 + ml];
    f32x4 bf;
    bf[0] = bv; bf[1] = bv; bf[2] = bv; bf[3] = bv;
    biasfrag[nt] = bf;
  }
  f32x4 qv[2][2];
  {
    const float* qp = qs + (mt * 16 + ml) * 64 + 8 * g;
    qv[0][0] = *(const f32x4*)(qp);
    qv[0][1] = *(const f32x4*)(qp + 4);
    qv[1][0] = *(const f32x4*)(qp + 32);
    qv[1][1] = *(const f32x4*)(qp + 36);
  }
  __syncthreads();  // s_kvb ready

  // ---- MFMA j-loop (R15-proven; per-tile wave mapping wl = w&7) ----
  float accs[2][4] = {};
  int jbeg = wl * 26;
  int jend = jbeg + 26;
  if (jend > KK) jend = KK;
  const float* kvbl = s_kvb + 8 * g;
#pragma unroll 2
  for (int j = jbeg; j < jend; j++) {
    const float* kp = kvbl + j * 64;
    f32x4 kv[2][2];
    kv[0][0] = *(const f32x4*)(kp);
    kv[0][1] = *(const f32x4*)(kp + 4);
    kv[1][0] = *(const f32x4*)(kp + 32);
    kv[1][1] = *(const f32x4*)(kp + 36);

    short8 afrag[2];
#pragma unroll
    for (int kh = 0; kh < 2; kh++)
#pragma unroll
      for (int hf = 0; hf < 2; hf++)
#pragma unroll
        for (int i = 0; i < 4; i++) {
          float h = fmaxf(qv[kh][hf][i] + kv[kh][hf][i], 0.f);
          afrag[kh][hf * 4 + i] = f2bf(h);
        }

#pragma unroll
    for (int nt = 0; nt < 2; nt++) {
      f32x4 cacc = __builtin_amdgcn_mfma_f32_16x16x32_bf16(
          afrag[0], bfrag[nt][0], biasfrag[nt], 0, 0, 0);
      cacc = __builtin_amdgcn_mfma_f32_16x16x32_bf16(
          afrag[1], bfrag[nt][1], cacc, 0, 0, 0);
#pragma unroll
      for (int r = 0; r < 4; r++) accs[nt][r] += fmaxf(cacc[r], 0.f);
    }
  }

  __syncthreads();  // done reading s_kvb before aliasing as red
#pragma unroll
  for (int nt = 0; nt < 2; nt++)
#pragma unroll
    for (int r = 0; r < 4; r++)
      red[w][(4 * g + r) * 32 + nt * 16 + ml] = accs[nt][r];
  __syncthreads();
  // per-tile reduction: half h sums rows h*8..h*8+7, writes row h*8 at its
  // exclusive column -> race-free.
  {
    int h = t >> 9, cidx = t & 511;
    float sum = 0.f;
#pragma unroll
    for (int ww = 0; ww < 8; ww++) sum += red[h * 8 + ww][cidx];
    sum *= (1.0f / (float)KK);
    red[h * 8][cidx] = sum;
  }
  __syncthreads();

  if (t < 512) {
    int mt_e = t >> 8, tl = t & 255;
    int m = tl >> 4, dc = tl & 15;
    float o = mb3[dc];
#pragma unroll
    for (int n = 0; n < 32; n++) o += red[mt_e * 8][m * 32 + n] * mw3[n * 16 + dc];
    out[(bs_base + mt_e * 16 + m) * 16 + dc] = o;
  }
}

extern "C" void kernel_launch(void* const* d_in, const int* in_sizes, int n_in,
                              void* d_out, int out_size, void* d_ws, size_t ws_size,
                              hipStream_t stream) {
  const float* full = (const float*)d_in[0];
  const float* sw1  = (const float*)d_in[1];
  const float* sb1  = (const float*)d_in[2];
  const float* sw2  = (const float*)d_in[3];
  const float* sb2  = (const float*)d_in[4];
  const float* mw1  = (const float*)d_in[5];
  const float* mb1  = (const float*)d_in[6];
  const float* mw2  = (const float*)d_in[7];
  const float* mb2  = (const float*)d_in[8];
  const float* mw3  = (const float*)d_in[9];
  const float* mb3  = (const float*)d_in[10];
  float* out = (float*)d_out;

  mega_kernel<<<BB * SS / 32, 1024, 0, stream>>>(full, sw1, sb1, sw2, sb2, mw1,
                                                 mb1, mw2, mb2, mw3, mb3, out);
}

// Round 20
// 43.355 us; speedup vs baseline: 1.1266x; 1.1266x over previous
//
#include <hip/hip_runtime.h>
#include <hip/hip_bf16.h>

#define BB 4
#define SS 2048
#define DD 16
#define KK 204      // max(1, int(2048*0.1))
// bank-conflict-free permuted hist layout: bin b -> addr
#define HADDR(bb) ((((bb) & 63) << 5) | ((bb) >> 6))

typedef __attribute__((ext_vector_type(8))) short short8;
typedef __attribute__((ext_vector_type(4))) float f32x4;

__device__ inline short f2bf(float x) {
  __hip_bfloat16 b = __float2bfloat16(x);
  return *reinterpret_cast<short*>(&b);
}

// ---- K0: scores only (64 blocks x 128 thr; 1 row/thread) -- R11/R15 proven ----
__global__ void __launch_bounds__(128) score_kernel(
    const float* __restrict__ full, const float* __restrict__ sw1,
    const float* __restrict__ sb1, const float* __restrict__ sw2,
    const float* __restrict__ sb2, float* __restrict__ scores_g) {
  __shared__ float swT[32][16];   // [n][k]
  __shared__ float sb1s[32], sw2s[32];
  int t = threadIdx.x;
#pragma unroll
  for (int it = 0; it < 4; it++) {
    int idx = t + it * 128;       // 512
    int n = idx & 31, k = idx >> 5;
    swT[n][k] = sw1[k * 32 + n];
  }
  if (t < 32) { sb1s[t] = sb1[t]; sw2s[t] = sw2[t]; }

  int row = blockIdx.x * 128 + t;           // 0..8191
  const float* xp = full + row * DD;
  f32x4 x0 = *(const f32x4*)(xp);
  f32x4 x1 = *(const f32x4*)(xp + 4);
  f32x4 x2 = *(const f32x4*)(xp + 8);
  f32x4 x3 = *(const f32x4*)(xp + 12);
  __syncthreads();

  float sc = sb2[0];
#pragma unroll
  for (int n = 0; n < 32; n++) {
    const f32x4* wp = (const f32x4*)&swT[n][0];
    f32x4 w0 = wp[0], w1 = wp[1], w2 = wp[2], w3 = wp[3];
    float a = sb1s[n];
#pragma unroll
    for (int k = 0; k < 4; k++) a += x0[k] * w0[k];
#pragma unroll
    for (int k = 0; k < 4; k++) a += x1[k] * w1[k];
#pragma unroll
    for (int k = 0; k < 4; k++) a += x2[k] * w2[k];
#pragma unroll
    for (int k = 0; k < 4; k++) a += x3[k] * w3[k];
    sc += fmaxf(a, 0.f) * sw2s[n];
  }
  scores_g[row] = sc;
}

// ---- K2-mega (256 blocks x 1024 thr; 2 m-tiles/block, 1 block/CU) ----
// SINGLE-WAVE radix: keys go to LDS; wave 0 alone runs the 4-pass select
// wave-synchronously (no block barriers inside; boundary broadcast via
// ballot+shfl, hist in HADDR-permuted layout for 2-way-max bank aliasing).
// Block barriers: 24 -> 8. Waves 1-15 overlap frag/qv/wreg loads.
// Selection set identical to R18 (same keys, same boundary formula);
// s_idx order is the deterministic (lane,e) order (j-permutation only).
// key = monotone(score)<<11 | (2047-i); unique keys -> "key >= K*" == jax
// top_k set; 4 passes x 11 bits.
// MFMA frags (16x16x32 bf16): A lane l: [m=l&15][k=8*(l>>4)+i];
// B lane l: [k=8*(l>>4)+i][n=l&15]; D lane l reg r: [m=4*(l>>4)+r][n=l&15].
__global__ void __launch_bounds__(1024) mega_kernel(
    const float* __restrict__ full, const float* __restrict__ mw1,
    const float* __restrict__ mb1, const float* __restrict__ mw2,
    const float* __restrict__ mb2, const float* __restrict__ mw3,
    const float* __restrict__ mb3, const float* __restrict__ scores_g,
    float* __restrict__ out) {
  int bs_base = blockIdx.x * 32;     // 2 m-tiles of 16 rows
  int b = bs_base >> 11;             // 64 blocks per batch
  int t = threadIdx.x;
  int w = t >> 6;                    // 0..15
  int l = t & 63;
  int mt = w >> 3;                   // m-tile 0/1
  int wl = w & 7;                    // wave within tile
  int ml = l & 15;
  int g = l >> 4;

  __shared__ float s_kvb[KK * 64];   // 52224 B; aliased: hist+keys / red
  __shared__ float qs[32 * 64];      // 8 KB (both tiles)
  __shared__ float xs[32 * 16];      // 2 KB
  __shared__ float s_xsel[KK * DD];  // 12.75 KB
  __shared__ int s_idx[KK];
  int* hist = (int*)s_kvb;                               // 8 KB
  unsigned long long* s_keys =
      (unsigned long long*)(s_kvb + 2048);               // 16 KB
  float (*red)[512] = (float(*)[512])s_kvb;              // epilogue alias

  // keys -> LDS (2/thread) + raw rows
#pragma unroll
  for (int e = 0; e < 2; e++) {
    int i = t + e * 1024;
    unsigned u = __float_as_uint(scores_g[b * SS + i]);
    u = (u & 0x80000000u) ? ~u : (u | 0x80000000u);  // order-preserving asc
    s_keys[i] = ((unsigned long long)u << 11) | (unsigned)(SS - 1 - i);
  }
  if (t < 512) xs[t] = full[bs_base * DD + t];
  __syncthreads();  // B1: xs + keys visible

  // ---- qpart for both tiles ----
  {
    int r = t >> 5, n = t & 31;
    float q0 = 0.f, q1 = 0.f;
#pragma unroll
    for (int k = 0; k < 16; k++) {
      float xv = xs[r * 16 + k];
      q0 += xv * mw1[k * 64 + n];        // w_q = mw1[:16]
      q1 += xv * mw1[k * 64 + n + 32];
    }
    qs[r * 64 + n] = q0;
    qs[r * 64 + n + 32] = q1;
  }
  __syncthreads();  // B2: qs ready (keys already ready)

  // ---- single-wave radix select + compaction (wave 0 only) ----
  if (w == 0) {
    unsigned long long pfx = 0ull;
    int r = KK;
    for (int pass = 0; pass < 4; pass++) {
      int s = 33 - pass * 11;
#pragma unroll
      for (int z = 0; z < 32; z++) hist[l + 64 * z] = 0;   // conflict-free
      for (int e = 0; e < 32; e++) {
        unsigned long long ke = s_keys[l + 64 * e];
        if ((ke >> (s + 11)) == pfx)
          atomicAdd(&hist[HADDR((int)((ke >> s) & 0x7FF))], 1);
      }
      // lane l owns value-contiguous bins [l*32, l*32+32)
      int tot = 0;
#pragma unroll
      for (int z = 0; z < 32; z++) tot += hist[HADDR(l * 32 + z)];
      int incl = tot;  // inclusive suffix over lanes >= l
#pragma unroll
      for (int off = 1; off < 64; off <<= 1) {
        int o = __shfl_down(incl, off);
        incl += (l + off < 64) ? o : 0;
      }
      int sufn = incl - tot;  // bins above this lane's range
      long long fpfx = -1;
      int fr = 0;
      for (int z = 31; z >= 0; z--) {  // descending value within lane
        int cnt = hist[HADDR(l * 32 + z)];
        int sufs = sufn + cnt;
        if (sufs >= r && sufn < r) {   // exactly one (lane,z) matches
          fpfx = (long long)((pfx << 11) | (unsigned)(l * 32 + z));
          fr = r - sufn;
        }
        sufn = sufs;
      }
      unsigned long long bal = __ballot(fpfx >= 0);
      int src = __ffsll((long long)bal) - 1;
      pfx = (unsigned long long)__shfl((long long)fpfx, src);
      r = __shfl(fr, src);
    }
    unsigned long long kstar = pfx;
    // deterministic compaction ordered by (l, e)
    unsigned selmask = 0u;
    int c = 0;
    for (int e = 0; e < 32; e++) {
      if (s_keys[l + 64 * e] >= kstar) { selmask |= (1u << e); c++; }
    }
    int p = c;  // inclusive prefix over lanes <= l
#pragma unroll
    for (int off = 1; off < 64; off <<= 1) {
      int o = __shfl_up(p, off);
      p += (l >= off) ? o : 0;
    }
    int pos = p - c;
    for (int e = 0; e < 32; e++)
      if (selmask & (1u << e)) s_idx[pos++] = l + 64 * e;
  }

  // all waves: register fragment loads overlap wave 0's radix
  short8 bfrag[2][2];  // [ntile][khalf]
#pragma unroll
  for (int nt = 0; nt < 2; nt++)
#pragma unroll
    for (int kh = 0; kh < 2; kh++)
#pragma unroll
      for (int i = 0; i < 8; i++) {
        int k = kh * 32 + 8 * g + i;
        bfrag[nt][kh][i] = f2bf(mw2[k * 32 + nt * 16 + ml]);
      }
  f32x4 biasfrag[2];
#pragma unroll
  for (int nt = 0; nt < 2; nt++) {
    float bv = mb2[nt * 16 + ml];
    f32x4 bf;
    bf[0] = bv; bf[1] = bv; bf[2] = bv; bf[3] = bv;
    biasfrag[nt] = bf;
  }
  f32x4 qv[2][2];
  {
    const float* qp = qs + (mt * 16 + ml) * 64 + 8 * g;
    qv[0][0] = *(const f32x4*)(qp);
    qv[0][1] = *(const f32x4*)(qp + 4);
    qv[1][0] = *(const f32x4*)(qp + 32);
    qv[1][1] = *(const f32x4*)(qp + 36);
  }
  float wreg[16];
#pragma unroll
  for (int k = 0; k < 16; k++)
    wreg[k] = mw1[(16 + k) * 64 + l] + mw1[(32 + k) * 64 + l];
  float biasv = mb1[l];
  __syncthreads();  // B3: s_idx ready

  // ---- vectorized gather of selected rows (f32x4; 4 lanes per 64B row) ----
  {
    f32x4* dst = (f32x4*)s_xsel;
    for (int i = t; i < KK * 4; i += 1024) {
      int j = i >> 2, qu = i & 3;
      dst[i] = ((const f32x4*)(full + (b * SS + s_idx[j]) * DD))[qu];
    }
  }
  __syncthreads();  // B4: s_xsel ready; keys/hist dead

  // ---- kvb into LDS (wave w: j = w, w+16, ...; same inner FMA order) ----
  for (int j = w; j < KK; j += 16) {
    const f32x4* xr = (const f32x4*)(s_xsel + j * DD);
    f32x4 x0 = xr[0], x1 = xr[1], x2 = xr[2], x3 = xr[3];
    float a = biasv;
#pragma unroll
    for (int k = 0; k < 4; k++) a += x0[k] * wreg[k];
#pragma unroll
    for (int k = 0; k < 4; k++) a += x1[k] * wreg[4 + k];
#pragma unroll
    for (int k = 0; k < 4; k++) a += x2[k] * wreg[8 + k];
#pragma unroll
    for (int k = 0; k < 4; k++) a += x3[k] * wreg[12 + k];
    s_kvb[j * 64 + l] = a;
  }
  __syncthreads();  // B5: s_kvb ready

  // ---- MFMA j-loop (R15-proven; per-tile wave mapping wl = w&7) ----
  float accs[2][4] = {};
  int jbeg = wl * 26;
  int jend = jbeg + 26;
  if (jend > KK) jend = KK;
  const float* kvbl = s_kvb + 8 * g;
#pragma unroll 2
  for (int j = jbeg; j < jend; j++) {
    const float* kp = kvbl + j * 64;
    f32x4 kv[2][2];
    kv[0][0] = *(const f32x4*)(kp);
    kv[0][1] = *(const f32x4*)(kp + 4);
    kv[1][0] = *(const f32x4*)(kp + 32);
    kv[1][1] = *(const f32x4*)(kp + 36);

    short8 afrag[2];
#pragma unroll
    for (int kh = 0; kh < 2; kh++)
#pragma unroll
      for (int hf = 0; hf < 2; hf++)
#pragma unroll
        for (int i = 0; i < 4; i++) {
          float h = fmaxf(qv[kh][hf][i] + kv[kh][hf][i], 0.f);
          afrag[kh][hf * 4 + i] = f2bf(h);
        }

#pragma unroll
    for (int nt = 0; nt < 2; nt++) {
      f32x4 cacc = __builtin_amdgcn_mfma_f32_16x16x32_bf16(
          afrag[0], bfrag[nt][0], biasfrag[nt], 0, 0, 0);
      cacc = __builtin_amdgcn_mfma_f32_16x16x32_bf16(
          afrag[1], bfrag[nt][1], cacc, 0, 0, 0);
#pragma unroll
      for (int r = 0; r < 4; r++) accs[nt][r] += fmaxf(cacc[r], 0.f);
    }
  }

  __syncthreads();  // B6: done reading s_kvb before aliasing as red
#pragma unroll
  for (int nt = 0; nt < 2; nt++)
#pragma unroll
    for (int r = 0; r < 4; r++)
      red[w][(4 * g + r) * 32 + nt * 16 + ml] = accs[nt][r];
  __syncthreads();  // B7
  // per-tile reduction: half h sums rows h*8..h*8+7, writes row h*8 at its
  // exclusive column -> race-free.
  {
    int h = t >> 9, cidx = t & 511;
    float sum = 0.f;
#pragma unroll
    for (int ww = 0; ww < 8; ww++) sum += red[h * 8 + ww][cidx];
    sum *= (1.0f / (float)KK);
    red[h * 8][cidx] = sum;
  }
  __syncthreads();  // B8

  if (t < 512) {
    int mt_e = t >> 8, tl = t & 255;
    int m = tl >> 4, dc = tl & 15;
    float o = mb3[dc];
#pragma unroll
    for (int n = 0; n < 32; n++) o += red[mt_e * 8][m * 32 + n] * mw3[n * 16 + dc];
    out[(bs_base + mt_e * 16 + m) * 16 + dc] = o;
  }
}

extern "C" void kernel_launch(void* const* d_in, const int* in_sizes, int n_in,
                              void* d_out, int out_size, void* d_ws, size_t ws_size,
                              hipStream_t stream) {
  const float* full = (const float*)d_in[0];
  const float* sw1  = (const float*)d_in[1];
  const float* sb1  = (const float*)d_in[2];
  const float* sw2  = (const float*)d_in[3];
  const float* sb2  = (const float*)d_in[4];
  const float* mw1  = (const float*)d_in[5];
  const float* mb1  = (const float*)d_in[6];
  const float* mw2  = (const float*)d_in[7];
  const float* mb2  = (const float*)d_in[8];
  const float* mw3  = (const float*)d_in[9];
  const float* mb3  = (const float*)d_in[10];
  float* out = (float*)d_out;

  float* scores_g = (float*)d_ws;            // 8192 floats

  score_kernel<<<64, 128, 0, stream>>>(full, sw1, sb1, sw2, sb2, scores_g);
  mega_kernel<<<BB * SS / 32, 1024, 0, stream>>>(full, mw1, mb1, mw2, mb2, mw3,
                                                 mb3, scores_g, out);
}

// Round 21
// 36.720 us; speedup vs baseline: 1.3302x; 1.1807x over previous
//
#include <hip/hip_runtime.h>
#include <hip/hip_bf16.h>

#define BB 4
#define SS 2048
#define DD 16
#define KK 204      // max(1, int(2048*0.1))

typedef __attribute__((ext_vector_type(8))) short short8;
typedef __attribute__((ext_vector_type(4))) float f32x4;

__device__ inline short f2bf(float x) {
  __hip_bfloat16 b = __float2bfloat16(x);
  return *reinterpret_cast<short*>(&b);
}

// ---- K0: scores only (64 blocks x 128 thr; 1 row/thread) -- R11/R15 proven ----
__global__ void __launch_bounds__(128) score_kernel(
    const float* __restrict__ full, const float* __restrict__ sw1,
    const float* __restrict__ sb1, const float* __restrict__ sw2,
    const float* __restrict__ sb2, float* __restrict__ scores_g) {
  __shared__ float swT[32][16];   // [n][k]
  __shared__ float sb1s[32], sw2s[32];
  int t = threadIdx.x;
#pragma unroll
  for (int it = 0; it < 4; it++) {
    int idx = t + it * 128;       // 512
    int n = idx & 31, k = idx >> 5;
    swT[n][k] = sw1[k * 32 + n];
  }
  if (t < 32) { sb1s[t] = sb1[t]; sw2s[t] = sw2[t]; }

  int row = blockIdx.x * 128 + t;           // 0..8191
  const float* xp = full + row * DD;
  f32x4 x0 = *(const f32x4*)(xp);
  f32x4 x1 = *(const f32x4*)(xp + 4);
  f32x4 x2 = *(const f32x4*)(xp + 8);
  f32x4 x3 = *(const f32x4*)(xp + 12);
  __syncthreads();

  float sc = sb2[0];
#pragma unroll
  for (int n = 0; n < 32; n++) {
    const f32x4* wp = (const f32x4*)&swT[n][0];
    f32x4 w0 = wp[0], w1 = wp[1], w2 = wp[2], w3 = wp[3];
    float a = sb1s[n];
#pragma unroll
    for (int k = 0; k < 4; k++) a += x0[k] * w0[k];
#pragma unroll
    for (int k = 0; k < 4; k++) a += x1[k] * w1[k];
#pragma unroll
    for (int k = 0; k < 4; k++) a += x2[k] * w2[k];
#pragma unroll
    for (int k = 0; k < 4; k++) a += x3[k] * w3[k];
    sc += fmaxf(a, 0.f) * sw2s[n];
  }
  scores_g[row] = sc;
}

// ---- K2-mega (256 blocks x 1024 thr; 2 m-tiles/block, 1 block/CU) ----
// Per block: ONE radix select (R11-proven 1024-thread form, 2 keys/thread,
// redundant across blocks but deterministic -> identical set) + ONE gather +
// ONE kvb, serving TWO m-tiles' j-loops (waves 0-7 -> tile0, 8-15 -> tile1).
// Halves per-CU radix/gather/kvb work vs the 512-thr 2-blocks/CU form.
// key = monotone(score)<<11 | (2047-i); unique keys -> "key >= K*" == jax
// top_k set; 4 passes x 11 bits. hist aliases first 8KB of s_kvb; red
// (16x512) aliases s_kvb in the epilogue.
// MFMA frags (16x16x32 bf16): A lane l: [m=l&15][k=8*(l>>4)+i];
// B lane l: [k=8*(l>>4)+i][n=l&15]; D lane l reg r: [m=4*(l>>4)+r][n=l&15].
__global__ void __launch_bounds__(1024) mega_kernel(
    const float* __restrict__ full, const float* __restrict__ mw1,
    const float* __restrict__ mb1, const float* __restrict__ mw2,
    const float* __restrict__ mb2, const float* __restrict__ mw3,
    const float* __restrict__ mb3, const float* __restrict__ scores_g,
    float* __restrict__ out) {
  int bs_base = blockIdx.x * 32;     // 2 m-tiles of 16 rows
  int b = bs_base >> 11;             // 64 blocks per batch
  int t = threadIdx.x;
  int w = t >> 6;                    // 0..15
  int l = t & 63;
  int mt = w >> 3;                   // m-tile 0/1
  int wl = w & 7;                    // wave within tile
  int ml = l & 15;
  int g = l >> 4;

  __shared__ float s_kvb[KK * 64];   // 52224 B; aliased: hist / red
  __shared__ float qs[32 * 64];      // 8 KB (both tiles)
  __shared__ float xs[32 * 16];      // 2 KB
  __shared__ float s_xsel[KK * DD];  // 12.75 KB
  __shared__ int s_idx[KK];
  __shared__ int wtot[16];
  __shared__ unsigned long long s_pfx;
  __shared__ int s_r;
  int* hist = (int*)s_kvb;                    // first 2048 ints
  float (*red)[512] = (float(*)[512])s_kvb;   // epilogue alias (16x512)

  // keys from scores_g (2/thread, R11 mapping) + raw rows
  unsigned long long key[2];
#pragma unroll
  for (int e = 0; e < 2; e++) {
    int i = t + e * 1024;
    unsigned u = __float_as_uint(scores_g[b * SS + i]);
    u = (u & 0x80000000u) ? ~u : (u | 0x80000000u);  // order-preserving asc
    key[e] = ((unsigned long long)u << 11) | (unsigned)(SS - 1 - i);
  }
  if (t < 512) xs[t] = full[bs_base * DD + t];
  if (t == 0) { s_pfx = 0ull; s_r = KK; }
  __syncthreads();  // xs visible

  // ---- qpart for both tiles (r = 0..31); published by first radix barrier ----
  {
    int r = t >> 5, n = t & 31;
    float q0 = 0.f, q1 = 0.f;
#pragma unroll
    for (int k = 0; k < 16; k++) {
      float xv = xs[r * 16 + k];
      q0 += xv * mw1[k * 64 + n];        // w_q = mw1[:16]
      q1 += xv * mw1[k * 64 + n + 32];
    }
    qs[r * 64 + n] = q0;
    qs[r * 64 + n + 32] = q1;
  }

  // ---- radix select (R11-proven 1024-thread form) ----
  for (int pass = 0; pass < 4; pass++) {
    int s = 33 - pass * 11;
    hist[t] = 0;
    hist[t + 1024] = 0;
    __syncthreads();                    // hist zeroed; s_pfx/s_r/qs visible
    unsigned long long pfx = s_pfx;
    int r = s_r;
#pragma unroll
    for (int e = 0; e < 2; e++)
      if ((key[e] >> (s + 11)) == pfx)
        atomicAdd(&hist[(int)((key[e] >> s) & 0x7FF)], 1);
    __syncthreads();
    // thread owns bins 2t, 2t+1
    int loc0 = hist[2 * t], loc1 = hist[2 * t + 1];
    int ls0 = loc0 + loc1, ls1 = loc1;  // suffix sums within the pair
    int tot = ls0;
    int incl = tot;  // wave inclusive suffix-scan (lanes >= l)
#pragma unroll
    for (int off = 1; off < 64; off <<= 1) {
      int o = __shfl_down(incl, off);
      incl += (l + off < 64) ? o : 0;
    }
    if (l == 0) wtot[w] = incl;
    __syncthreads();
    int waveoff = 0;
    for (int ww = w + 1; ww < 16; ww++) waveoff += wtot[ww];
    int excl = waveoff + (incl - tot);  // sum over threads > t
    int sufs0 = ls0 + excl, sufs1 = ls1 + excl;
    if (sufs0 >= r && sufs1 < r) {      // bin 2t is the boundary
      s_pfx = (pfx << 11) | (unsigned)(2 * t);
      s_r = r - sufs1;
    }
    if (sufs1 >= r && excl < r) {       // bin 2t+1 is the boundary
      s_pfx = (pfx << 11) | (unsigned)(2 * t + 1);
      s_r = r - excl;
    }
    __syncthreads();
  }

  unsigned long long kstar = s_pfx;
  // deterministic compaction ordered by (t, e) -- R11-proven
  bool sel0 = (key[0] >= kstar), sel1 = (key[1] >= kstar);
  int c = (sel0 ? 1 : 0) + (sel1 ? 1 : 0);
  int p = c;  // wave inclusive prefix (lanes <= l)
#pragma unroll
  for (int off = 1; off < 64; off <<= 1) {
    int o = __shfl_up(p, off);
    p += (l >= off) ? o : 0;
  }
  if (l == 63) wtot[w] = p;
  __syncthreads();
  int base = 0;
  for (int ww = 0; ww < w; ww++) base += wtot[ww];
  int pos = base + p - c;
  if (sel0) s_idx[pos++] = t;
  if (sel1) s_idx[pos] = t + 1024;
  __syncthreads();  // s_idx ready

  // ---- vectorized gather of selected rows (f32x4; 4 lanes per 64B row) ----
  {
    f32x4* dst = (f32x4*)s_xsel;
    for (int i = t; i < KK * 4; i += 1024) {
      int j = i >> 2, qu = i & 3;
      dst[i] = ((const f32x4*)(full + (b * SS + s_idx[j]) * DD))[qu];
    }
  }
  float wreg[16];
#pragma unroll
  for (int k = 0; k < 16; k++)
    wreg[k] = mw1[(16 + k) * 64 + l] + mw1[(32 + k) * 64 + l];
  float biasv = mb1[l];
  __syncthreads();  // s_xsel ready; hist region free

  // ---- kvb into LDS (wave w: j = w, w+16, ...; same inner FMA order) ----
  for (int j = w; j < KK; j += 16) {
    const f32x4* xr = (const f32x4*)(s_xsel + j * DD);
    f32x4 x0 = xr[0], x1 = xr[1], x2 = xr[2], x3 = xr[3];
    float a = biasv;
#pragma unroll
    for (int k = 0; k < 4; k++) a += x0[k] * wreg[k];
#pragma unroll
    for (int k = 0; k < 4; k++) a += x1[k] * wreg[4 + k];
#pragma unroll
    for (int k = 0; k < 4; k++) a += x2[k] * wreg[8 + k];
#pragma unroll
    for (int k = 0; k < 4; k++) a += x3[k] * wreg[12 + k];
    s_kvb[j * 64 + l] = a;
  }

  short8 bfrag[2][2];  // [ntile][khalf]
#pragma unroll
  for (int nt = 0; nt < 2; nt++)
#pragma unroll
    for (int kh = 0; kh < 2; kh++)
#pragma unroll
      for (int i = 0; i < 8; i++) {
        int k = kh * 32 + 8 * g + i;
        bfrag[nt][kh][i] = f2bf(mw2[k * 32 + nt * 16 + ml]);
      }
  f32x4 biasfrag[2];
#pragma unroll
  for (int nt = 0; nt < 2; nt++) {
    float bv = mb2[nt * 16 + ml];
    f32x4 bf;
    bf[0] = bv; bf[1] = bv; bf[2] = bv; bf[3] = bv;
    biasfrag[nt] = bf;
  }
  f32x4 qv[2][2];
  {
    const float* qp = qs + (mt * 16 + ml) * 64 + 8 * g;
    qv[0][0] = *(const f32x4*)(qp);
    qv[0][1] = *(const f32x4*)(qp + 4);
    qv[1][0] = *(const f32x4*)(qp + 32);
    qv[1][1] = *(const f32x4*)(qp + 36);
  }
  __syncthreads();  // s_kvb ready

  // ---- MFMA j-loop (R15-proven; per-tile wave mapping wl = w&7) ----
  float accs[2][4] = {};
  int jbeg = wl * 26;
  int jend = jbeg + 26;
  if (jend > KK) jend = KK;
  const float* kvbl = s_kvb + 8 * g;
#pragma unroll 2
  for (int j = jbeg; j < jend; j++) {
    const float* kp = kvbl + j * 64;
    f32x4 kv[2][2];
    kv[0][0] = *(const f32x4*)(kp);
    kv[0][1] = *(const f32x4*)(kp + 4);
    kv[1][0] = *(const f32x4*)(kp + 32);
    kv[1][1] = *(const f32x4*)(kp + 36);

    short8 afrag[2];
#pragma unroll
    for (int kh = 0; kh < 2; kh++)
#pragma unroll
      for (int hf = 0; hf < 2; hf++)
#pragma unroll
        for (int i = 0; i < 4; i++) {
          float h = fmaxf(qv[kh][hf][i] + kv[kh][hf][i], 0.f);
          afrag[kh][hf * 4 + i] = f2bf(h);
        }

#pragma unroll
    for (int nt = 0; nt < 2; nt++) {
      f32x4 cacc = __builtin_amdgcn_mfma_f32_16x16x32_bf16(
          afrag[0], bfrag[nt][0], biasfrag[nt], 0, 0, 0);
      cacc = __builtin_amdgcn_mfma_f32_16x16x32_bf16(
          afrag[1], bfrag[nt][1], cacc, 0, 0, 0);
#pragma unroll
      for (int r = 0; r < 4; r++) accs[nt][r] += fmaxf(cacc[r], 0.f);
    }
  }

  __syncthreads();  // done reading s_kvb before aliasing as red
#pragma unroll
  for (int nt = 0; nt < 2; nt++)
#pragma unroll
    for (int r = 0; r < 4; r++)
      red[w][(4 * g + r) * 32 + nt * 16 + ml] = accs[nt][r];
  __syncthreads();
  // per-tile reduction: half h sums rows h*8..h*8+7, writes row h*8 at its
  // exclusive column -> race-free.
  {
    int h = t >> 9, cidx = t & 511;
    float sum = 0.f;
#pragma unroll
    for (int ww = 0; ww < 8; ww++) sum += red[h * 8 + ww][cidx];
    sum *= (1.0f / (float)KK);
    red[h * 8][cidx] = sum;
  }
  __syncthreads();

  if (t < 512) {
    int mt_e = t >> 8, tl = t & 255;
    int m = tl >> 4, dc = tl & 15;
    float o = mb3[dc];
#pragma unroll
    for (int n = 0; n < 32; n++) o += red[mt_e * 8][m * 32 + n] * mw3[n * 16 + dc];
    out[(bs_base + mt_e * 16 + m) * 16 + dc] = o;
  }
}

extern "C" void kernel_launch(void* const* d_in, const int* in_sizes, int n_in,
                              void* d_out, int out_size, void* d_ws, size_t ws_size,
                              hipStream_t stream) {
  const float* full = (const float*)d_in[0];
  const float* sw1  = (const float*)d_in[1];
  const float* sb1  = (const float*)d_in[2];
  const float* sw2  = (const float*)d_in[3];
  const float* sb2  = (const float*)d_in[4];
  const float* mw1  = (const float*)d_in[5];
  const float* mb1  = (const float*)d_in[6];
  const float* mw2  = (const float*)d_in[7];
  const float* mb2  = (const float*)d_in[8];
  const float* mw3  = (const float*)d_in[9];
  const float* mb3  = (const float*)d_in[10];
  float* out = (float*)d_out;

  float* scores_g = (float*)d_ws;            // 8192 floats

  score_kernel<<<64, 128, 0, stream>>>(full, sw1, sb1, sw2, sb2, scores_g);
  mega_kernel<<<BB * SS / 32, 1024, 0, stream>>>(full, mw1, mb1, mw2, mb2, mw3,
                                                 mb3, scores_g, out);
}